// Round 19
// baseline (107.864 us; speedup 1.0000x reference)
//
#include <hip/hip_runtime.h>

typedef _Float16 f16;
typedef _Float16 f16x2 __attribute__((ext_vector_type(2)));
typedef _Float16 f16x4 __attribute__((ext_vector_type(4)));
typedef _Float16 f16x8 __attribute__((ext_vector_type(8)));
typedef float f32x4 __attribute__((ext_vector_type(4)));
typedef float f32x16 __attribute__((ext_vector_type(16)));

#define MFMA16(a, b, c) __builtin_amdgcn_mfma_f32_16x16x32_f16((a), (b), (c), 0, 0, 0)
#define MFMA32(a, b, c) __builtin_amdgcn_mfma_f32_32x32x16_f16((a), (b), (c), 0, 0, 0)

typedef const __attribute__((address_space(1))) void gv_t;
typedef __attribute__((address_space(3))) void lv_t;

// ---------------- fused fp32 -> f16 convert (x, qkv_w, out_w in one launch) ------
__global__ void cvt_all(const float* __restrict__ x, const float* __restrict__ qw,
                        const float* __restrict__ ow, f16* __restrict__ d) {
    int i = (blockIdx.x * 256 + threadIdx.x) * 4;   // flat f16-element index / 4
    const float* s;
    int off;
    if (i < 4194304) { s = x; off = i; }
    else if (i < 4980736) { s = qw; off = i - 4194304; }
    else { s = ow; off = i - 4980736; }
    float4 v = *(const float4*)(s + off);
    f16x4 o = {(f16)v.x, (f16)v.y, (f16)v.z, (f16)v.w};
    *(f16x4*)(d + i) = o;
}

// ---------------- NT GEMM, 128x128 tile, BK=32, dbuf LDS via global_load_lds ----
// (256,4): 4 waves/SIMD (128-reg cap) -- LDS is 34KB so 4 WG/CU fit; staging via
// global_load_lds keeps VGPR use low enough for the 128 cap (audit ~120-130).
// MODE 0: epilogue via LDS-bounce -> fully coalesced 16B/lane packed stores.
//   Kp[b][kb=s>>5][kc=d>>4][lane=(d>>3&1)*32+(s&31)][e=d&7]
//   Vp[b][db=d>>5][kw=s>>4][lane=(s>>3&1)*32+(d&31)][e=s&7]
// MODE 1: A via global_load_lds (AO), fp32 C + bias (direct store).
// MODE 2: A = on-the-fly split-K combine of Opart pairs (reg-staged blend).
template<int MODE>
__global__ __launch_bounds__(256, 4) void gemm_nt(const f16* __restrict__ A, const f16* __restrict__ W,
                                                  const float* __restrict__ bias, float* __restrict__ Cf,
                                                  f16* __restrict__ Qb, f16* __restrict__ Kb,
                                                  f16* __restrict__ Vt,
                                                  const f16* __restrict__ Opart,
                                                  const float* __restrict__ Ml) {
    // SM aliases: As(buf) = SM[buf*4096 ..], Bs(buf) = SM[8192 + buf*4096 ..],
    // epilogue tile Es[128][136] = SM[0 .. 17407].
    __shared__ f16 SM[17408];
    const int m0 = blockIdx.x * 128, n0 = blockIdx.y * 128;
    const int tid = threadIdx.x;
    const int w = tid >> 6, l = tid & 63;
    const int wm = w >> 1, wn = w & 1;
    const int lr = l & 15, lg = l >> 4;
    const int R = w * 16 + (l >> 2);
    const int ldsoff = w * 512;
    const int lidx = ldsoff + l * 8;
    const f16* ag = A + (size_t)(m0 + R) * 512 + (l & 3) * 8;
    const f16* bg = W + (size_t)(n0 + R) * 512 + (l & 3) * 8;
    (void)lidx;

    // MODE 2 prologue: per-row combine weights + partial pointers (rows R, R+64)
    float fA[2], fB[2];
    const f16* opA[2];
    const f16* opB[2];
    if (MODE == 2) {
#pragma unroll
        for (int i = 0; i < 2; ++i) {
            int m = m0 + R + 64 * i;
            int b = m >> 11, qq = m & 2047;
            int qb = qq >> 5, qr = qq & 31;
            int bid0 = qb * 8 + 2 * b, bid1 = bid0 + 1;
            float m0v = Ml[((size_t)bid0 * 32 + qr) * 2];
            float l0v = Ml[((size_t)bid0 * 32 + qr) * 2 + 1];
            float m1v = Ml[((size_t)bid1 * 32 + qr) * 2];
            float l1v = Ml[((size_t)bid1 * 32 + qr) * 2 + 1];
            float M = fmaxf(m0v, m1v);
            float w0 = __expf(m0v - M) * l0v;
            float w1 = __expf(m1v - M) * l1v;
            float inv = 1.f / (w0 + w1);
            fA[i] = w0 * inv;
            fB[i] = w1 * inv;
            opA[i] = Opart + ((size_t)bid0 * 32 + qr) * 512 + (l & 3) * 8;
            opB[i] = Opart + ((size_t)bid1 * 32 + qr) * 512 + (l & 3) * 8;
        }
    }

#if __has_builtin(__builtin_amdgcn_global_load_lds)
#define GLDS(gp, lp) __builtin_amdgcn_global_load_lds((gv_t*)(gp), (lv_t*)(lp), 16, 0, 0)
#define A1STAGE(k0, buf) do {                                          \
        GLDS(ag + (k0), &SM[(buf) * 4096 + ldsoff]);                   \
        GLDS(ag + 64 * 512 + (k0), &SM[(buf) * 4096 + ldsoff + 2048]); \
    } while (0)
#define BSTAGE(k0, buf) do {                                                  \
        GLDS(bg + (k0), &SM[8192 + (buf) * 4096 + ldsoff]);                   \
        GLDS(bg + 64 * 512 + (k0), &SM[8192 + (buf) * 4096 + ldsoff + 2048]); \
    } while (0)
#else
#define A1STAGE(k0, buf) do {                                                             \
        *(f16x8*)&SM[(buf) * 4096 + lidx] = *(const f16x8*)(ag + (k0));                   \
        *(f16x8*)&SM[(buf) * 4096 + lidx + 2048] = *(const f16x8*)(ag + 64 * 512 + (k0)); \
    } while (0)
#define BSTAGE(k0, buf) do {                                                                     \
        *(f16x8*)&SM[8192 + (buf) * 4096 + lidx] = *(const f16x8*)(bg + (k0));                   \
        *(f16x8*)&SM[8192 + (buf) * 4096 + lidx + 2048] = *(const f16x8*)(bg + 64 * 512 + (k0)); \
    } while (0)
#endif
// MODE 2: reg-staged blended A (exact combine numerics, f32 blend -> f16)
#define A2STAGE(k0, buf) do {                                                  \
        _Pragma("unroll")                                                      \
        for (int i = 0; i < 2; ++i) {                                          \
            f16x8 a0 = *(const f16x8*)(opA[i] + (k0));                         \
            f16x8 a1 = *(const f16x8*)(opB[i] + (k0));                         \
            f16x8 bl;                                                          \
            _Pragma("unroll")                                                  \
            for (int jj = 0; jj < 8; ++jj)                                     \
                bl[jj] = (f16)(fA[i] * (float)a0[jj] + fB[i] * (float)a1[jj]); \
            *(f16x8*)&SM[(buf) * 4096 + lidx + 2048 * i] = bl;                 \
        }                                                                      \
    } while (0)
#define STAGE(k0, buf) do {                    \
        if (MODE == 2) A2STAGE(k0, buf);       \
        else A1STAGE(k0, buf);                 \
        BSTAGE(k0, buf);                       \
    } while (0)

    f32x4 acc[4][4] = {};
    STAGE(0, 0);
    __syncthreads();
    int cur = 0;
    for (int k0 = 0; k0 < 512; k0 += 32) {
        if (k0 + 32 < 512) STAGE(k0 + 32, cur ^ 1);
        f16x8 af[4], bf[4];
#pragma unroll
        for (int i = 0; i < 4; ++i)
            af[i] = *(f16x8*)&SM[cur * 4096 + (64 * wm + 16 * i + lr) * 32 + lg * 8];
#pragma unroll
        for (int i = 0; i < 4; ++i)
            bf[i] = *(f16x8*)&SM[8192 + cur * 4096 + (64 * wn + 16 * i + lr) * 32 + lg * 8];
        __builtin_amdgcn_s_setprio(1);
#pragma unroll
        for (int mf = 0; mf < 4; ++mf)
#pragma unroll
            for (int nf = 0; nf < 4; ++nf) acc[mf][nf] = MFMA16(af[mf], bf[nf], acc[mf][nf]);
        __builtin_amdgcn_s_setprio(0);
        __syncthreads();
        cur ^= 1;
    }

    if (MODE == 0) {
        // ---- phase 1: acc -> Es[128][136] (f16, Q-scale applied for Q tiles) ----
        const bool isQ = (n0 < 512);
#pragma unroll
        for (int mf = 0; mf < 4; ++mf)
#pragma unroll
            for (int nf = 0; nf < 4; ++nf)
#pragma unroll
                for (int r = 0; r < 4; ++r) {
                    int rr = 64 * wm + 16 * mf + 4 * lg + r;
                    int cc = 64 * wn + 16 * nf + lr;
                    float val = acc[mf][nf][r] + bias[n0 + cc];
                    SM[rr * 136 + cc] = (f16)(isQ ? val * 0.04419417382415922f : val);
                }
        __syncthreads();
        // ---- phase 2: coalesced packed 16B/lane stores per tile kind ----
        const int bb2 = m0 >> 11, s0 = m0 & 2047;
        if (n0 < 512) {
            // Q: row-major, 2048 chunks of 16B
#pragma unroll
            for (int it = 0; it < 8; ++it) {
                int lin = it * 256 + tid;
                int row = lin >> 4, cc8 = (lin & 15) * 8;
                f16x8 h = *(f16x8*)&SM[row * 136 + cc8];
                *(f16x8*)&Qb[((size_t)(bb2 * 2048 + s0 + row)) * 512 + n0 + cc8] = h;
            }
        } else if (n0 < 1024) {
            // K: 32 fragment-runs of 1KB, lane-contiguous by construction
            const int d0t = n0 - 512;
#pragma unroll
            for (int it = 0; it < 8; ++it) {
                int lin = it * 256 + tid;
                int run = lin >> 6, li = lin & 63;
                int sc = run >> 3, dc = run & 7;
                int kb = (s0 >> 5) + sc, kc = (d0t >> 4) + dc;
                int row = 32 * sc + (li & 31);
                int col = 16 * dc + (li >> 5) * 8;
                f16x8 h = *(f16x8*)&SM[row * 136 + col];
                *(f16x8*)&Kb[(((size_t)(bb2 * 64 + kb)) * 32 + kc) * 512 + (size_t)li * 8] = h;
            }
        } else {
            // V: 32 fragment-runs of 1KB; chunk elements stride Es rows (gather)
            const int d0t = n0 - 1024;
#pragma unroll
            for (int it = 0; it < 8; ++it) {
                int lin = it * 256 + tid;
                int run = lin >> 6, li = lin & 63;
                int dvc = run >> 3, svc = run & 7;
                int db = (d0t >> 5) + dvc, kw = (s0 >> 4) + svc;
                int colE = 32 * dvc + (li & 31);
                int rowE0 = 16 * svc + (li >> 5) * 8;
                f16x8 h;
#pragma unroll
                for (int j = 0; j < 8; ++j) h[j] = SM[(rowE0 + j) * 136 + colE];
                *(f16x8*)&Vt[(((size_t)(bb2 * 16 + db)) * 128 + kw) * 512 + (size_t)li * 8] = h;
            }
        }
    } else {
        // MODE 1/2: fp32 C + bias, direct store (row-major, adequately coalesced)
#pragma unroll
        for (int mf = 0; mf < 4; ++mf)
#pragma unroll
            for (int nf = 0; nf < 4; ++nf)
#pragma unroll
                for (int r = 0; r < 4; ++r) {
                    int rr = 64 * wm + 16 * mf + 4 * lg + r;
                    int cc = 64 * wn + 16 * nf + lr;
                    int m = m0 + rr, e = n0 + cc;
                    Cf[(size_t)m * 512 + e] = acc[mf][nf][r] + bias[e];
                }
    }
#undef STAGE
#undef A2STAGE
#undef A1STAGE
#undef BSTAGE
}

// ---------------- flash attention: 8 waves, QBLK=32, KEYTILE=256, 32x32 MFMA ----
// r10/r14-proven config (64.5us): kt-top batch preload of K ring(8) + V pairs(8),
// ring refills inside QK^T/PV, NSPLIT=2 (512 WGs), no setprio, no cross-kt reload.
template<int NSPLIT, bool PART>
__global__ __launch_bounds__(512, 2) void flash_attn(const f16* __restrict__ Qb, const f16* __restrict__ Kb,
                                                     const f16* __restrict__ Vt, f16* __restrict__ AO,
                                                     f16* __restrict__ Opart, float* __restrict__ Ml) {
    __shared__ f16 Qs[32 * 512];   // [row][chunk^(row&7)] on 16B chunks
    __shared__ f16 P_lds[32 * 256];
    __shared__ float mbuf[32][8];
    __shared__ float lbuf[32][8];
    __shared__ float abuf[32];

    const int bid = blockIdx.x;
    const int xcd = bid & 7, slot = bid >> 3;
    const int b = xcd >> 1;
    const int t = slot * 2 + (xcd & 1);      // 0 .. 64*NSPLIT-1
    const int q0 = (t / NSPLIT) * 32;
    const int ks = t % NSPLIT;
    const int SPLITLEN = 2048 / NSPLIT;
    const int nkt = SPLITLEN / 256;

    const int tid = threadIdx.x;
    const int j = tid >> 6, l = tid & 63;
    const int q = l & 31, lh = l >> 5;

    const f16* Qg = Qb + ((size_t)b * 2048 + q0) * 512;
    const f16* Kg = Kb + ((size_t)b * 64 + (size_t)ks * (SPLITLEN / 32)) * 32 * 512;
    const f16* Vg = Vt + (size_t)b * 16 * 128 * 512 + (size_t)(ks * (SPLITLEN / 16)) * 512;

    // stage Q tile [32][512] into swizzled LDS (coalesced 16B per lane)
    for (int i = tid; i < 2048; i += 512) {
        int r = i >> 6, ch = i & 63;
        *(f16x8*)&Qs[r * 512 + ((ch ^ (r & 7)) * 8)] = *(const f16x8*)&Qg[(size_t)r * 512 + ch * 8];
    }

    f32x16 o[2] = {};
    float m_st = -1e30f, l_st = 0.f;
    char* Pq = (char*)&P_lds[0];
    const uint swz = ((uint)(q & 15)) << 4;
    const int qbase = q * 512, qx = q & 7;
    __syncthreads();

    for (int kt = 0; kt < nkt; ++kt) {
        const int key0 = kt * 256;
        const f16* kp = Kg + ((size_t)((key0 >> 5) + j) * 32) * 512 + (size_t)l * 8;
        const f16* vpb = Vg + ((size_t)(2 * j) * 128 + (key0 >> 4)) * 512 + (size_t)l * 8;
        // ---- batch preload: K ring (8) + V pairs for kk=0..3 (8) ----
        f16x8 kr[8], vr[8];
#pragma unroll
        for (int i = 0; i < 8; ++i) kr[i] = *(const f16x8*)(kp + (size_t)i * 512);
#pragma unroll
        for (int i = 0; i < 4; ++i) {
            vr[2 * i] = *(const f16x8*)(vpb + (size_t)i * 512);
            vr[2 * i + 1] = *(const f16x8*)(vpb + (size_t)(128 + i) * 512);
        }
        // ---- QK^T (swapped): S^T[32 keys j-slice][32 q]; K ring prefetch ----
        f32x16 sA = {}, sB = {};
#pragma unroll
        for (int kc = 0; kc < 32; kc += 2) {
            f16x8 k0 = kr[kc & 7];
            f16x8 k1 = kr[(kc & 7) + 1];
            if (kc < 24) {
                kr[kc & 7] = *(const f16x8*)(kp + (size_t)(kc + 8) * 512);
                kr[(kc & 7) + 1] = *(const f16x8*)(kp + (size_t)(kc + 9) * 512);
            }
            f16x8 q0f = *(f16x8*)&Qs[qbase + (((2 * kc + lh) ^ qx) * 8)];
            f16x8 q1f = *(f16x8*)&Qs[qbase + (((2 * kc + 2 + lh) ^ qx) * 8)];
            sA = MFMA32(k0, q0f, sA);
            sB = MFMA32(k1, q1f, sB);
        }
        float s[16];
#pragma unroll
        for (int r = 0; r < 16; ++r) s[r] = sA[r] + sB[r];
        // ---- in-register partial max over own 32 keys ----
        float mt = s[0];
#pragma unroll
        for (int r = 1; r < 16; ++r) mt = fmaxf(mt, s[r]);
        mt = fmaxf(mt, __shfl_xor(mt, 32));
        if (l < 32) mbuf[q][j] = mt;
        __syncthreads();  // barrier 1
        float mnew = m_st;
        {
            float4 mv0 = *(float4*)&mbuf[q][0];
            float4 mv1 = *(float4*)&mbuf[q][4];
            mnew = fmaxf(mnew, fmaxf(fmaxf(mv0.x, mv0.y), fmaxf(mv0.z, mv0.w)));
            mnew = fmaxf(mnew, fmaxf(fmaxf(mv1.x, mv1.y), fmaxf(mv1.z, mv1.w)));
        }
        float alpha = __expf(m_st - mnew);
        if (l < 32) abuf[q] = alpha;
        float ps = 0.f;
#pragma unroll
        for (int r = 0; r < 16; ++r) {
            s[r] = __expf(s[r] - mnew);
            ps += s[r];
        }
        ps += __shfl_xor(ps, 32);
        if (l < 32) lbuf[q][j] = ps;
        // pack P -> P_lds[q][key], XOR-swizzled, f16x4 chunks (keys e+8i+4lh+32j)
        {
            const uint rowb = (uint)q * 512;
#pragma unroll
            for (int i = 0; i < 4; ++i) {
                int key = 8 * i + 4 * lh + 32 * j;
                f16x4 pk = {(f16)s[4 * i], (f16)s[4 * i + 1], (f16)s[4 * i + 2], (f16)s[4 * i + 3]};
                *(f16x4*)(Pq + ((rowb + (uint)key * 2) ^ swz)) = pk;
            }
        }
        m_st = mnew;
        __syncthreads();  // barrier 2
        // ---- combine l across 8 j-waves ----
        {
            float4 lv0 = *(float4*)&lbuf[q][0];
            float4 lv1 = *(float4*)&lbuf[q][4];
            l_st = l_st * alpha + ((lv0.x + lv0.y) + (lv0.z + lv0.w))
                                + ((lv1.x + lv1.y) + (lv1.z + lv1.w));
        }
        // ---- rescale O: alpha per O-reg's q-row via abuf broadcast ----
        float av[4][4];
#pragma unroll
        for (int g = 0; g < 4; ++g) {
            float4 a4 = *(float4*)&abuf[8 * g + 4 * lh];
            av[g][0] = a4.x; av[g][1] = a4.y; av[g][2] = a4.z; av[g][3] = a4.w;
        }
#pragma unroll
        for (int dt = 0; dt < 2; ++dt)
#pragma unroll
            for (int r = 0; r < 16; ++r) o[dt][r] *= av[r >> 2][r & 3];
        // ---- PV: O[32q][64d j-slice] += P[32q][256k] * V; V ring prefetch ----
#pragma unroll
        for (int kk = 0; kk < 16; ++kk) {
            f16x8 v0 = vr[(kk & 3) * 2];
            f16x8 v1 = vr[(kk & 3) * 2 + 1];
            if (kk < 12) {
                vr[(kk & 3) * 2] = *(const f16x8*)(vpb + (size_t)(kk + 4) * 512);
                vr[(kk & 3) * 2 + 1] = *(const f16x8*)(vpb + (size_t)(128 + kk + 4) * 512);
            }
            f16x8 paf = *(f16x8*)(Pq + (((uint)q * 512 + (uint)(16 * kk + 8 * lh) * 2) ^ swz));
            o[0] = MFMA32(paf, v0, o[0]);
            o[1] = MFMA32(paf, v1, o[1]);
        }
    }
    __syncthreads();  // protect abuf reuse below against stragglers in PV
    if (l < 32) abuf[q] = l_st;
    if (PART && l < 32 && j == 0) {
        Ml[((size_t)bid * 32 + q) * 2 + 0] = m_st;
        Ml[((size_t)bid * 32 + q) * 2 + 1] = l_st;
    }
    __syncthreads();
    float iv[4][4];
#pragma unroll
    for (int g = 0; g < 4; ++g) {
        float4 a4 = *(float4*)&abuf[8 * g + 4 * lh];
        iv[g][0] = 1.f / a4.x; iv[g][1] = 1.f / a4.y; iv[g][2] = 1.f / a4.z; iv[g][3] = 1.f / a4.w;
    }
    f16* op = PART ? (Opart + (size_t)bid * 32 * 512 + 64 * j)
                   : (AO + ((size_t)(b * 2048 + q0)) * 512 + 64 * j);
#pragma unroll
    for (int r = 0; r < 16; ++r) {
        int qr = (r & 3) + 8 * (r >> 2) + 4 * lh;
        float inv = iv[r >> 2][r & 3];
#pragma unroll
        for (int dt = 0; dt < 2; ++dt)
            op[(size_t)qr * 512 + 32 * dt + q] = (f16)(o[dt][r] * inv);
    }
}

// ---------------- launch ----------------
extern "C" void kernel_launch(void* const* d_in, const int* in_sizes, int n_in,
                              void* d_out, int out_size, void* d_ws, size_t ws_size,
                              hipStream_t stream) {
    (void)in_sizes; (void)n_in; (void)out_size;
    const float* x = (const float*)d_in[0];
    const float* qkv_w = (const float*)d_in[1];
    const float* qkv_b = (const float*)d_in[2];
    const float* out_w = (const float*)d_in[3];
    const float* out_b = (const float*)d_in[4];
    char* ws = (char*)d_ws;
    f16* xh    = (f16*)(ws + 0);
    f16* wqkvh = (f16*)(ws + 8388608);
    f16* wouth = (f16*)(ws + 9961472);
    f16* Qb    = (f16*)(ws + 10485760);
    f16* Kb    = (f16*)(ws + 18874368);  // packed K fragments, 8,388,608
    f16* Vt    = (f16*)(ws + 27262976);  // packed V fragments, 8,388,608
    f16* AO    = (f16*)(ws + 35651584);  // fallback path only
    f16* Opart = (f16*)(ws + 44040192);               // 512*32*512*2 = 16,777,216
    float* Ml  = (float*)(ws + 44040192 + 16777216);  // 512*32*2*4 = 131,072
    const size_t NEED = 44040192ull + 16777216ull + 131072ull;

    cvt_all<<<5120, 256, 0, stream>>>(x, qkv_w, out_w, xh);

    gemm_nt<0><<<dim3(64, 12), 256, 0, stream>>>(xh, wqkvh, qkv_b, nullptr, Qb, Kb, Vt,
                                                 nullptr, nullptr);

    if (ws_size >= NEED) {
        flash_attn<2, true><<<512, 512, 0, stream>>>(Qb, Kb, Vt, nullptr, Opart, Ml);
        gemm_nt<2><<<dim3(64, 4), 256, 0, stream>>>(Opart, wouth, out_b, (float*)d_out,
                                                    nullptr, nullptr, nullptr, Opart, Ml);
    } else {
        flash_attn<1, false><<<256, 512, 0, stream>>>(Qb, Kb, Vt, AO, nullptr, nullptr);
        gemm_nt<1><<<dim3(64, 4), 256, 0, stream>>>(AO, wouth, out_b, (float*)d_out,
                                                    nullptr, nullptr, nullptr, nullptr, nullptr);
    }
}

// Round 20
// 107.405 us; speedup vs baseline: 1.0043x; 1.0043x over previous
//
#include <hip/hip_runtime.h>

typedef _Float16 f16;
typedef _Float16 f16x2 __attribute__((ext_vector_type(2)));
typedef _Float16 f16x4 __attribute__((ext_vector_type(4)));
typedef _Float16 f16x8 __attribute__((ext_vector_type(8)));
typedef float f32x4 __attribute__((ext_vector_type(4)));
typedef float f32x16 __attribute__((ext_vector_type(16)));

#define MFMA16(a, b, c) __builtin_amdgcn_mfma_f32_16x16x32_f16((a), (b), (c), 0, 0, 0)
#define MFMA32(a, b, c) __builtin_amdgcn_mfma_f32_32x32x16_f16((a), (b), (c), 0, 0, 0)

typedef const __attribute__((address_space(1))) void gv_t;
typedef __attribute__((address_space(3))) void lv_t;

// ---------------- fused fp32 -> f16 convert (x, qkv_w, out_w in one launch) ------
__global__ void cvt_all(const float* __restrict__ x, const float* __restrict__ qw,
                        const float* __restrict__ ow, f16* __restrict__ d) {
    int i = (blockIdx.x * 256 + threadIdx.x) * 4;   // flat f16-element index / 4
    const float* s;
    int off;
    if (i < 4194304) { s = x; off = i; }
    else if (i < 4980736) { s = qw; off = i - 4194304; }
    else { s = ow; off = i - 4980736; }
    float4 v = *(const float4*)(s + off);
    f16x4 o = {(f16)v.x, (f16)v.y, (f16)v.z, (f16)v.w};
    *(f16x4*)(d + i) = o;
}

// ---------------- NT GEMM, 128x128 tile, BK=32, dbuf LDS via global_load_lds ----
// (256,4): 4 waves/SIMD (128-reg cap) -- LDS is 34KB so 4 WG/CU fit; staging via
// global_load_lds keeps VGPR use low enough for the 128 cap (audit ~120-130).
// MODE 0: epilogue via LDS-bounce -> fully coalesced 16B/lane packed stores.
//   Kp[b][kb=s>>5][kc=d>>4][lane=(d>>3&1)*32+(s&31)][e=d&7]
//   Vp[b][db=d>>5][kw=s>>4][lane=(s>>3&1)*32+(d&31)][e=s&7]
// MODE 1: A via global_load_lds (AO), fp32 C + bias (direct store).
// MODE 2: A = on-the-fly split-K combine of Opart pairs (reg-staged blend).
template<int MODE>
__global__ __launch_bounds__(256, 4) void gemm_nt(const f16* __restrict__ A, const f16* __restrict__ W,
                                                  const float* __restrict__ bias, float* __restrict__ Cf,
                                                  f16* __restrict__ Qb, f16* __restrict__ Kb,
                                                  f16* __restrict__ Vt,
                                                  const f16* __restrict__ Opart,
                                                  const float* __restrict__ Ml) {
    // SM aliases: As(buf) = SM[buf*4096 ..], Bs(buf) = SM[8192 + buf*4096 ..],
    // epilogue tile Es[128][136] = SM[0 .. 17407].
    __shared__ f16 SM[17408];
    const int m0 = blockIdx.x * 128, n0 = blockIdx.y * 128;
    const int tid = threadIdx.x;
    const int w = tid >> 6, l = tid & 63;
    const int wm = w >> 1, wn = w & 1;
    const int lr = l & 15, lg = l >> 4;
    const int R = w * 16 + (l >> 2);
    const int ldsoff = w * 512;
    const int lidx = ldsoff + l * 8;
    const f16* ag = A + (size_t)(m0 + R) * 512 + (l & 3) * 8;
    const f16* bg = W + (size_t)(n0 + R) * 512 + (l & 3) * 8;
    (void)lidx;

    // MODE 2 prologue: per-row combine weights + partial pointers (rows R, R+64)
    float fA[2], fB[2];
    const f16* opA[2];
    const f16* opB[2];
    if (MODE == 2) {
#pragma unroll
        for (int i = 0; i < 2; ++i) {
            int m = m0 + R + 64 * i;
            int b = m >> 11, qq = m & 2047;
            int qb = qq >> 5, qr = qq & 31;
            int bid0 = qb * 8 + 2 * b, bid1 = bid0 + 1;
            float m0v = Ml[((size_t)bid0 * 32 + qr) * 2];
            float l0v = Ml[((size_t)bid0 * 32 + qr) * 2 + 1];
            float m1v = Ml[((size_t)bid1 * 32 + qr) * 2];
            float l1v = Ml[((size_t)bid1 * 32 + qr) * 2 + 1];
            float M = fmaxf(m0v, m1v);
            float w0 = __expf(m0v - M) * l0v;
            float w1 = __expf(m1v - M) * l1v;
            float inv = 1.f / (w0 + w1);
            fA[i] = w0 * inv;
            fB[i] = w1 * inv;
            opA[i] = Opart + ((size_t)bid0 * 32 + qr) * 512 + (l & 3) * 8;
            opB[i] = Opart + ((size_t)bid1 * 32 + qr) * 512 + (l & 3) * 8;
        }
    }

#if __has_builtin(__builtin_amdgcn_global_load_lds)
#define GLDS(gp, lp) __builtin_amdgcn_global_load_lds((gv_t*)(gp), (lv_t*)(lp), 16, 0, 0)
#define A1STAGE(k0, buf) do {                                          \
        GLDS(ag + (k0), &SM[(buf) * 4096 + ldsoff]);                   \
        GLDS(ag + 64 * 512 + (k0), &SM[(buf) * 4096 + ldsoff + 2048]); \
    } while (0)
#define BSTAGE(k0, buf) do {                                                  \
        GLDS(bg + (k0), &SM[8192 + (buf) * 4096 + ldsoff]);                   \
        GLDS(bg + 64 * 512 + (k0), &SM[8192 + (buf) * 4096 + ldsoff + 2048]); \
    } while (0)
#else
#define A1STAGE(k0, buf) do {                                                             \
        *(f16x8*)&SM[(buf) * 4096 + lidx] = *(const f16x8*)(ag + (k0));                   \
        *(f16x8*)&SM[(buf) * 4096 + lidx + 2048] = *(const f16x8*)(ag + 64 * 512 + (k0)); \
    } while (0)
#define BSTAGE(k0, buf) do {                                                                     \
        *(f16x8*)&SM[8192 + (buf) * 4096 + lidx] = *(const f16x8*)(bg + (k0));                   \
        *(f16x8*)&SM[8192 + (buf) * 4096 + lidx + 2048] = *(const f16x8*)(bg + 64 * 512 + (k0)); \
    } while (0)
#endif
// MODE 2: reg-staged blended A (exact combine numerics, f32 blend -> f16)
#define A2STAGE(k0, buf) do {                                                  \
        _Pragma("unroll")                                                      \
        for (int i = 0; i < 2; ++i) {                                          \
            f16x8 a0 = *(const f16x8*)(opA[i] + (k0));                         \
            f16x8 a1 = *(const f16x8*)(opB[i] + (k0));                         \
            f16x8 bl;                                                          \
            _Pragma("unroll")                                                  \
            for (int jj = 0; jj < 8; ++jj)                                     \
                bl[jj] = (f16)(fA[i] * (float)a0[jj] + fB[i] * (float)a1[jj]); \
            *(f16x8*)&SM[(buf) * 4096 + lidx + 2048 * i] = bl;                 \
        }                                                                      \
    } while (0)
#define STAGE(k0, buf) do {                    \
        if (MODE == 2) A2STAGE(k0, buf);       \
        else A1STAGE(k0, buf);                 \
        BSTAGE(k0, buf);                       \
    } while (0)

    f32x4 acc[4][4] = {};
    STAGE(0, 0);
    __syncthreads();
    int cur = 0;
    for (int k0 = 0; k0 < 512; k0 += 32) {
        if (k0 + 32 < 512) STAGE(k0 + 32, cur ^ 1);
        f16x8 af[4], bf[4];
#pragma unroll
        for (int i = 0; i < 4; ++i)
            af[i] = *(f16x8*)&SM[cur * 4096 + (64 * wm + 16 * i + lr) * 32 + lg * 8];
#pragma unroll
        for (int i = 0; i < 4; ++i)
            bf[i] = *(f16x8*)&SM[8192 + cur * 4096 + (64 * wn + 16 * i + lr) * 32 + lg * 8];
        __builtin_amdgcn_s_setprio(1);
#pragma unroll
        for (int mf = 0; mf < 4; ++mf)
#pragma unroll
            for (int nf = 0; nf < 4; ++nf) acc[mf][nf] = MFMA16(af[mf], bf[nf], acc[mf][nf]);
        __builtin_amdgcn_s_setprio(0);
        __syncthreads();
        cur ^= 1;
    }

    if (MODE == 0) {
        // ---- phase 1: acc -> Es[128][136] (f16, Q-scale applied for Q tiles) ----
        const bool isQ = (n0 < 512);
#pragma unroll
        for (int mf = 0; mf < 4; ++mf)
#pragma unroll
            for (int nf = 0; nf < 4; ++nf)
#pragma unroll
                for (int r = 0; r < 4; ++r) {
                    int rr = 64 * wm + 16 * mf + 4 * lg + r;
                    int cc = 64 * wn + 16 * nf + lr;
                    float val = acc[mf][nf][r] + bias[n0 + cc];
                    SM[rr * 136 + cc] = (f16)(isQ ? val * 0.04419417382415922f : val);
                }
        __syncthreads();
        // ---- phase 2: coalesced packed 16B/lane stores per tile kind ----
        const int bb2 = m0 >> 11, s0 = m0 & 2047;
        if (n0 < 512) {
            // Q: row-major, 2048 chunks of 16B
#pragma unroll
            for (int it = 0; it < 8; ++it) {
                int lin = it * 256 + tid;
                int row = lin >> 4, cc8 = (lin & 15) * 8;
                f16x8 h = *(f16x8*)&SM[row * 136 + cc8];
                *(f16x8*)&Qb[((size_t)(bb2 * 2048 + s0 + row)) * 512 + n0 + cc8] = h;
            }
        } else if (n0 < 1024) {
            // K: 32 fragment-runs of 1KB, lane-contiguous by construction
            const int d0t = n0 - 512;
#pragma unroll
            for (int it = 0; it < 8; ++it) {
                int lin = it * 256 + tid;
                int run = lin >> 6, li = lin & 63;
                int sc = run >> 3, dc = run & 7;
                int kb = (s0 >> 5) + sc, kc = (d0t >> 4) + dc;
                int row = 32 * sc + (li & 31);
                int col = 16 * dc + (li >> 5) * 8;
                f16x8 h = *(f16x8*)&SM[row * 136 + col];
                *(f16x8*)&Kb[(((size_t)(bb2 * 64 + kb)) * 32 + kc) * 512 + (size_t)li * 8] = h;
            }
        } else {
            // V: 32 fragment-runs of 1KB; chunk elements stride Es rows (gather)
            const int d0t = n0 - 1024;
#pragma unroll
            for (int it = 0; it < 8; ++it) {
                int lin = it * 256 + tid;
                int run = lin >> 6, li = lin & 63;
                int dvc = run >> 3, svc = run & 7;
                int db = (d0t >> 5) + dvc, kw = (s0 >> 4) + svc;
                int colE = 32 * dvc + (li & 31);
                int rowE0 = 16 * svc + (li >> 5) * 8;
                f16x8 h;
#pragma unroll
                for (int j = 0; j < 8; ++j) h[j] = SM[(rowE0 + j) * 136 + colE];
                *(f16x8*)&Vt[(((size_t)(bb2 * 16 + db)) * 128 + kw) * 512 + (size_t)li * 8] = h;
            }
        }
    } else {
        // MODE 1/2: fp32 C + bias, direct store (row-major, adequately coalesced)
#pragma unroll
        for (int mf = 0; mf < 4; ++mf)
#pragma unroll
            for (int nf = 0; nf < 4; ++nf)
#pragma unroll
                for (int r = 0; r < 4; ++r) {
                    int rr = 64 * wm + 16 * mf + 4 * lg + r;
                    int cc = 64 * wn + 16 * nf + lr;
                    int m = m0 + rr, e = n0 + cc;
                    Cf[(size_t)m * 512 + e] = acc[mf][nf][r] + bias[e];
                }
    }
#undef STAGE
#undef A2STAGE
#undef A1STAGE
#undef BSTAGE
}

// ---------------- flash attention: 8 waves, QBLK=32, KEYTILE=256, 32x32 MFMA ----
// r10/r14-proven config (64.5us): kt-top batch preload of K ring(8) + V pairs(8),
// ring refills inside QK^T/PV, NSPLIT=2 (512 WGs), no setprio, no cross-kt reload.
template<int NSPLIT, bool PART>
__global__ __launch_bounds__(512, 2) void flash_attn(const f16* __restrict__ Qb, const f16* __restrict__ Kb,
                                                     const f16* __restrict__ Vt, f16* __restrict__ AO,
                                                     f16* __restrict__ Opart, float* __restrict__ Ml) {
    __shared__ f16 Qs[32 * 512];   // [row][chunk^(row&7)] on 16B chunks
    __shared__ f16 P_lds[32 * 256];
    __shared__ float mbuf[32][8];
    __shared__ float lbuf[32][8];
    __shared__ float abuf[32];

    const int bid = blockIdx.x;
    const int xcd = bid & 7, slot = bid >> 3;
    const int b = xcd >> 1;
    const int t = slot * 2 + (xcd & 1);      // 0 .. 64*NSPLIT-1
    const int q0 = (t / NSPLIT) * 32;
    const int ks = t % NSPLIT;
    const int SPLITLEN = 2048 / NSPLIT;
    const int nkt = SPLITLEN / 256;

    const int tid = threadIdx.x;
    const int j = tid >> 6, l = tid & 63;
    const int q = l & 31, lh = l >> 5;

    const f16* Qg = Qb + ((size_t)b * 2048 + q0) * 512;
    const f16* Kg = Kb + ((size_t)b * 64 + (size_t)ks * (SPLITLEN / 32)) * 32 * 512;
    const f16* Vg = Vt + (size_t)b * 16 * 128 * 512 + (size_t)(ks * (SPLITLEN / 16)) * 512;

    // stage Q tile [32][512] into swizzled LDS (coalesced 16B per lane)
    for (int i = tid; i < 2048; i += 512) {
        int r = i >> 6, ch = i & 63;
        *(f16x8*)&Qs[r * 512 + ((ch ^ (r & 7)) * 8)] = *(const f16x8*)&Qg[(size_t)r * 512 + ch * 8];
    }

    f32x16 o[2] = {};
    float m_st = -1e30f, l_st = 0.f;
    char* Pq = (char*)&P_lds[0];
    const uint swz = ((uint)(q & 15)) << 4;
    const int qbase = q * 512, qx = q & 7;
    __syncthreads();

    for (int kt = 0; kt < nkt; ++kt) {
        const int key0 = kt * 256;
        const f16* kp = Kg + ((size_t)((key0 >> 5) + j) * 32) * 512 + (size_t)l * 8;
        const f16* vpb = Vg + ((size_t)(2 * j) * 128 + (key0 >> 4)) * 512 + (size_t)l * 8;
        // ---- batch preload: K ring (8) + V pairs for kk=0..3 (8) ----
        f16x8 kr[8], vr[8];
#pragma unroll
        for (int i = 0; i < 8; ++i) kr[i] = *(const f16x8*)(kp + (size_t)i * 512);
#pragma unroll
        for (int i = 0; i < 4; ++i) {
            vr[2 * i] = *(const f16x8*)(vpb + (size_t)i * 512);
            vr[2 * i + 1] = *(const f16x8*)(vpb + (size_t)(128 + i) * 512);
        }
        // ---- QK^T (swapped): S^T[32 keys j-slice][32 q]; K ring prefetch ----
        f32x16 sA = {}, sB = {};
#pragma unroll
        for (int kc = 0; kc < 32; kc += 2) {
            f16x8 k0 = kr[kc & 7];
            f16x8 k1 = kr[(kc & 7) + 1];
            if (kc < 24) {
                kr[kc & 7] = *(const f16x8*)(kp + (size_t)(kc + 8) * 512);
                kr[(kc & 7) + 1] = *(const f16x8*)(kp + (size_t)(kc + 9) * 512);
            }
            f16x8 q0f = *(f16x8*)&Qs[qbase + (((2 * kc + lh) ^ qx) * 8)];
            f16x8 q1f = *(f16x8*)&Qs[qbase + (((2 * kc + 2 + lh) ^ qx) * 8)];
            sA = MFMA32(k0, q0f, sA);
            sB = MFMA32(k1, q1f, sB);
        }
        float s[16];
#pragma unroll
        for (int r = 0; r < 16; ++r) s[r] = sA[r] + sB[r];
        // ---- in-register partial max over own 32 keys ----
        float mt = s[0];
#pragma unroll
        for (int r = 1; r < 16; ++r) mt = fmaxf(mt, s[r]);
        mt = fmaxf(mt, __shfl_xor(mt, 32));
        if (l < 32) mbuf[q][j] = mt;
        __syncthreads();  // barrier 1
        float mnew = m_st;
        {
            float4 mv0 = *(float4*)&mbuf[q][0];
            float4 mv1 = *(float4*)&mbuf[q][4];
            mnew = fmaxf(mnew, fmaxf(fmaxf(mv0.x, mv0.y), fmaxf(mv0.z, mv0.w)));
            mnew = fmaxf(mnew, fmaxf(fmaxf(mv1.x, mv1.y), fmaxf(mv1.z, mv1.w)));
        }
        float alpha = __expf(m_st - mnew);
        if (l < 32) abuf[q] = alpha;
        float ps = 0.f;
#pragma unroll
        for (int r = 0; r < 16; ++r) {
            s[r] = __expf(s[r] - mnew);
            ps += s[r];
        }
        ps += __shfl_xor(ps, 32);
        if (l < 32) lbuf[q][j] = ps;
        // pack P -> P_lds[q][key], XOR-swizzled, f16x4 chunks (keys e+8i+4lh+32j)
        {
            const uint rowb = (uint)q * 512;
#pragma unroll
            for (int i = 0; i < 4; ++i) {
                int key = 8 * i + 4 * lh + 32 * j;
                f16x4 pk = {(f16)s[4 * i], (f16)s[4 * i + 1], (f16)s[4 * i + 2], (f16)s[4 * i + 3]};
                *(f16x4*)(Pq + ((rowb + (uint)key * 2) ^ swz)) = pk;
            }
        }
        m_st = mnew;
        __syncthreads();  // barrier 2
        // ---- combine l across 8 j-waves ----
        {
            float4 lv0 = *(float4*)&lbuf[q][0];
            float4 lv1 = *(float4*)&lbuf[q][4];
            l_st = l_st * alpha + ((lv0.x + lv0.y) + (lv0.z + lv0.w))
                                + ((lv1.x + lv1.y) + (lv1.z + lv1.w));
        }
        // ---- rescale O: alpha per O-reg's q-row via abuf broadcast ----
        float av[4][4];
#pragma unroll
        for (int g = 0; g < 4; ++g) {
            float4 a4 = *(float4*)&abuf[8 * g + 4 * lh];
            av[g][0] = a4.x; av[g][1] = a4.y; av[g][2] = a4.z; av[g][3] = a4.w;
        }
#pragma unroll
        for (int dt = 0; dt < 2; ++dt)
#pragma unroll
            for (int r = 0; r < 16; ++r) o[dt][r] *= av[r >> 2][r & 3];
        // ---- PV: O[32q][64d j-slice] += P[32q][256k] * V; V ring prefetch ----
#pragma unroll
        for (int kk = 0; kk < 16; ++kk) {
            f16x8 v0 = vr[(kk & 3) * 2];
            f16x8 v1 = vr[(kk & 3) * 2 + 1];
            if (kk < 12) {
                vr[(kk & 3) * 2] = *(const f16x8*)(vpb + (size_t)(kk + 4) * 512);
                vr[(kk & 3) * 2 + 1] = *(const f16x8*)(vpb + (size_t)(128 + kk + 4) * 512);
            }
            f16x8 paf = *(f16x8*)(Pq + (((uint)q * 512 + (uint)(16 * kk + 8 * lh) * 2) ^ swz));
            o[0] = MFMA32(paf, v0, o[0]);
            o[1] = MFMA32(paf, v1, o[1]);
        }
    }
    __syncthreads();  // protect abuf reuse below against stragglers in PV
    if (l < 32) abuf[q] = l_st;
    if (PART && l < 32 && j == 0) {
        Ml[((size_t)bid * 32 + q) * 2 + 0] = m_st;
        Ml[((size_t)bid * 32 + q) * 2 + 1] = l_st;
    }
    __syncthreads();
    float iv[4][4];
#pragma unroll
    for (int g = 0; g < 4; ++g) {
        float4 a4 = *(float4*)&abuf[8 * g + 4 * lh];
        iv[g][0] = 1.f / a4.x; iv[g][1] = 1.f / a4.y; iv[g][2] = 1.f / a4.z; iv[g][3] = 1.f / a4.w;
    }
    f16* op = PART ? (Opart + (size_t)bid * 32 * 512 + 64 * j)
                   : (AO + ((size_t)(b * 2048 + q0)) * 512 + 64 * j);
#pragma unroll
    for (int r = 0; r < 16; ++r) {
        int qr = (r & 3) + 8 * (r >> 2) + 4 * lh;
        float inv = iv[r >> 2][r & 3];
#pragma unroll
        for (int dt = 0; dt < 2; ++dt)
            op[(size_t)qr * 512 + 32 * dt + q] = (f16)(o[dt][r] * inv);
    }
}

// ---------------- launch ----------------
extern "C" void kernel_launch(void* const* d_in, const int* in_sizes, int n_in,
                              void* d_out, int out_size, void* d_ws, size_t ws_size,
                              hipStream_t stream) {
    (void)in_sizes; (void)n_in; (void)out_size;
    const float* x = (const float*)d_in[0];
    const float* qkv_w = (const float*)d_in[1];
    const float* qkv_b = (const float*)d_in[2];
    const float* out_w = (const float*)d_in[3];
    const float* out_b = (const float*)d_in[4];
    char* ws = (char*)d_ws;
    f16* xh    = (f16*)(ws + 0);
    f16* wqkvh = (f16*)(ws + 8388608);
    f16* wouth = (f16*)(ws + 9961472);
    f16* Qb    = (f16*)(ws + 10485760);
    f16* Kb    = (f16*)(ws + 18874368);  // packed K fragments, 8,388,608
    f16* Vt    = (f16*)(ws + 27262976);  // packed V fragments, 8,388,608
    f16* AO    = (f16*)(ws + 35651584);  // fallback path only
    f16* Opart = (f16*)(ws + 44040192);               // 512*32*512*2 = 16,777,216
    float* Ml  = (float*)(ws + 44040192 + 16777216);  // 512*32*2*4 = 131,072
    const size_t NEED = 44040192ull + 16777216ull + 131072ull;

    cvt_all<<<5120, 256, 0, stream>>>(x, qkv_w, out_w, xh);

    gemm_nt<0><<<dim3(64, 12), 256, 0, stream>>>(xh, wqkvh, qkv_b, nullptr, Qb, Kb, Vt,
                                                 nullptr, nullptr);

    if (ws_size >= NEED) {
        flash_attn<2, true><<<512, 512, 0, stream>>>(Qb, Kb, Vt, nullptr, Opart, Ml);
        gemm_nt<2><<<dim3(64, 4), 256, 0, stream>>>(Opart, wouth, out_b, (float*)d_out,
                                                    nullptr, nullptr, nullptr, Opart, Ml);
    } else {
        flash_attn<1, false><<<256, 512, 0, stream>>>(Qb, Kb, Vt, AO, nullptr, nullptr);
        gemm_nt<1><<<dim3(64, 4), 256, 0, stream>>>(AO, wouth, out_b, (float*)d_out,
                                                    nullptr, nullptr, nullptr, nullptr, nullptr);
    }
}